// Round 7
// baseline (354.937 us; speedup 1.0000x reference)
//
#include <hip/hip_runtime.h>
#include <hip/hip_bf16.h>

#define N_NODES 50000
#define N_EDGES 600000
#define HID 128
#define LN_EPS 1e-5f

#define SCAN_BLOCK 1024
#define SCAN_NBLK ((N_NODES + SCAN_BLOCK - 1) / SCAN_BLOCK)   // 49

// f32 -> bf16 with round-to-nearest-even (values are finite; no NaN guard)
static __device__ __forceinline__ unsigned short f2bf(float f) {
    union { float f; unsigned u; } v; v.f = f;
    unsigned u = v.u;
    u += 0x7fffu + ((u >> 16) & 1u);
    return (unsigned short)(u >> 16);
}

// ---------------------------------------------------------------- CSR build
__global__ __launch_bounds__(256) void count_kernel(const int* __restrict__ ei,
                                                    int* __restrict__ deg, int E) {
    int i = blockIdx.x * blockDim.x + threadIdx.x;
    if (i < E) atomicAdd(&deg[ei[E + i]], 1);
}

__global__ __launch_bounds__(SCAN_BLOCK) void deg_partial_kernel(const int* __restrict__ deg,
                                                                 int* __restrict__ partials, int n) {
    int t = threadIdx.x;
    int i = blockIdx.x * SCAN_BLOCK + t;
    int v = (i < n) ? deg[i] : 0;
    int s = v;
#pragma unroll
    for (int off = 1; off < 64; off <<= 1) s += __shfl_xor(s, off);
    __shared__ int ws[SCAN_BLOCK / 64];
    if ((t & 63) == 0) ws[t >> 6] = s;
    __syncthreads();
    if (t == 0) {
        int tot = 0;
#pragma unroll
        for (int w = 0; w < SCAN_BLOCK / 64; ++w) tot += ws[w];
        partials[blockIdx.x] = tot;
    }
}

__global__ __launch_bounds__(64) void scan_partials_kernel(int* __restrict__ partials,
                                                           int* __restrict__ row_ptr, int nblk) {
    int lane = threadIdx.x;
    int v = (lane < nblk) ? partials[lane] : 0;
    int incl = v;
#pragma unroll
    for (int off = 1; off < 64; off <<= 1) {
        int x = __shfl_up(incl, off);
        if (lane >= off) incl += x;
    }
    if (lane < nblk) partials[lane] = incl - v;     // exclusive block offset
    if (lane == 63) row_ptr[N_NODES] = incl;        // grand total
}

__global__ __launch_bounds__(SCAN_BLOCK) void scan_final_kernel(const int* __restrict__ deg,
                                                                const int* __restrict__ partials,
                                                                int* __restrict__ row_ptr,
                                                                int* __restrict__ cursor,
                                                                float* __restrict__ inv_cnt, int n) {
    int t = threadIdx.x;
    int i = blockIdx.x * SCAN_BLOCK + t;
    int v = (i < n) ? deg[i] : 0;
    int lane = t & 63, wid = t >> 6;
    int incl = v;
#pragma unroll
    for (int off = 1; off < 64; off <<= 1) {
        int x = __shfl_up(incl, off);
        if (lane >= off) incl += x;
    }
    __shared__ int ws[SCAN_BLOCK / 64];
    if (lane == 63) ws[wid] = incl;
    __syncthreads();
    int woff = 0;
    for (int w = 0; w < wid; ++w) woff += ws[w];
    int excl = partials[blockIdx.x] + woff + (incl - v);
    if (i < n) {
        row_ptr[i] = excl;
        cursor[i]  = excl;
        inv_cnt[i] = 1.0f / (float)(v + 1);          // +1 self loop
    }
}

__global__ __launch_bounds__(256) void fill_kernel(const int* __restrict__ ei,
                                                   int* __restrict__ cursor,
                                                   int* __restrict__ col, int E) {
    int i = blockIdx.x * blockDim.x + threadIdx.x;
    if (i < E) {
        int s = ei[i];
        int d = ei[E + i];
        int p = atomicAdd(&cursor[d], 1);
        col[p] = s;
    }
}

// ---------------------------------------------------------------- GEMM  hb = bf16(A@W + b)
// A:[N,K] f32, W:[K,128] f32 staged in LDS, out bf16 [N,128].
template <int K>
__global__ __launch_bounds__(256) void gemm_kernel(const float* __restrict__ A,
                                                   const float* __restrict__ W,
                                                   const float* __restrict__ b,
                                                   unsigned short* __restrict__ out, int N) {
    __shared__ float Wl[K * 128];
    __shared__ float bl[128];
    int t = threadIdx.x;
    for (int i = t; i < K * 32; i += 256)
        ((float4*)Wl)[i] = ((const float4*)W)[i];
    if (t < 128) bl[t] = b[t];
    __syncthreads();

    int cg = t & 31;              // columns 4*cg .. 4*cg+3
    int rs = t >> 5;              // 0..7
    int r0 = blockIdx.x * 32 + rs * 4;

    const float4* Wl4 = (const float4*)Wl;
    float4 bias = ((const float4*)bl)[cg];
    float4 acc0 = bias, acc1 = bias, acc2 = bias, acc3 = bias;

    int ra = min(r0 + 0, N - 1);
    int rb = min(r0 + 1, N - 1);
    int rc = min(r0 + 2, N - 1);
    int rd = min(r0 + 3, N - 1);

    for (int k = 0; k < K; k += 4) {
        float4 w0 = Wl4[(k + 0) * 32 + cg];
        float4 w1 = Wl4[(k + 1) * 32 + cg];
        float4 w2 = Wl4[(k + 2) * 32 + cg];
        float4 w3 = Wl4[(k + 3) * 32 + cg];
        float4 a0 = *(const float4*)&A[(size_t)ra * K + k];
        float4 a1 = *(const float4*)&A[(size_t)rb * K + k];
        float4 a2 = *(const float4*)&A[(size_t)rc * K + k];
        float4 a3 = *(const float4*)&A[(size_t)rd * K + k];
#define FMA4(ACC, AV)                                                          \
        ACC.x += AV.x * w0.x; ACC.y += AV.x * w0.y; ACC.z += AV.x * w0.z; ACC.w += AV.x * w0.w; \
        ACC.x += AV.y * w1.x; ACC.y += AV.y * w1.y; ACC.z += AV.y * w1.z; ACC.w += AV.y * w1.w; \
        ACC.x += AV.z * w2.x; ACC.y += AV.z * w2.y; ACC.z += AV.z * w2.z; ACC.w += AV.z * w2.w; \
        ACC.x += AV.w * w3.x; ACC.y += AV.w * w3.y; ACC.z += AV.w * w3.z; ACC.w += AV.w * w3.w;
        FMA4(acc0, a0)
        FMA4(acc1, a1)
        FMA4(acc2, a2)
        FMA4(acc3, a3)
#undef FMA4
    }
#define STORE_ROW(R, ACC)                                                      \
    if (r0 + R < N) {                                                          \
        ushort4 p;                                                             \
        p.x = f2bf(ACC.x); p.y = f2bf(ACC.y);                                  \
        p.z = f2bf(ACC.z); p.w = f2bf(ACC.w);                                  \
        *(ushort4*)&out[(size_t)(r0 + R) * 128 + 4 * cg] = p;                  \
    }
    STORE_ROW(0, acc0)
    STORE_ROW(1, acc1)
    STORE_ROW(2, acc2)
    STORE_ROW(3, acc3)
#undef STORE_ROW
}

// ------------------------------------------------- aggregate + mean + ReLU + LN
// one wave per node; lane holds cols {2*lane, 2*lane+1}; h rows are bf16 (256B).
__global__ __launch_bounds__(256) void agg_norm_kernel(
    const unsigned short* __restrict__ hb,  // [N,128] bf16 post-linear
    const int* __restrict__ row_ptr,
    const int* __restrict__ col,
    const float* __restrict__ inv_cnt,
    const float* __restrict__ g, const float* __restrict__ be,
    float* __restrict__ out, int N) {
    int wave = (int)((blockIdx.x * (size_t)blockDim.x + threadIdx.x) >> 6);
    int lane = threadIdx.x & 63;
    if (wave >= N) return;
    int n = wave;
    const unsigned* h2 = (const unsigned*)hb;   // 2 bf16 per load

    union { unsigned u; float f; } cvt;
    float ax, ay;
    {
        unsigned u = h2[(size_t)n * 64 + lane];            // self loop
        cvt.u = u << 16;          ax = cvt.f;
        cvt.u = u & 0xffff0000u;  ay = cvt.f;
    }
    int beg = row_ptr[n], end = row_ptr[n + 1];
    int cnt = end - beg;
    int myc = (lane < cnt) ? col[beg + lane] : 0;    // covers deg <= 64 (typ. ~12)
    for (int e = 0; e < cnt; ++e) {
        int j = (e < 64) ? __shfl(myc, e) : col[beg + e];
        unsigned u = h2[(size_t)j * 64 + lane];
        cvt.u = u << 16;          ax += cvt.f;
        cvt.u = u & 0xffff0000u;  ay += cvt.f;
    }
    float ic = inv_cnt[n];
    float s0 = fmaxf(ax * ic, 0.0f);
    float s1 = fmaxf(ay * ic, 0.0f);
    float sum = s0 + s1;
    float sq  = s0 * s0 + s1 * s1;
#pragma unroll
    for (int off = 1; off < 64; off <<= 1) {
        sum += __shfl_xor(sum, off);
        sq  += __shfl_xor(sq, off);
    }
    float mu  = sum * (1.0f / 128.0f);
    float var = sq * (1.0f / 128.0f) - mu * mu;
    float rs  = rsqrtf(var + LN_EPS);
    float2 gg = ((const float2*)g)[lane];
    float2 bb = ((const float2*)be)[lane];
    float2 o;
    o.x = gg.x * (s0 - mu) * rs + bb.x;
    o.y = gg.y * (s1 - mu) * rs + bb.y;
    ((float2*)out)[(size_t)n * 64 + lane] = o;
}

// ---------------------------------------------------------------- launch
extern "C" void kernel_launch(void* const* d_in, const int* in_sizes, int n_in,
                              void* d_out, int out_size, void* d_ws, size_t ws_size,
                              hipStream_t stream) {
    const float* x  = (const float*)d_in[0];
    const int*   ei = (const int*)d_in[1];
    const float* W1 = (const float*)d_in[2];
    const float* b1 = (const float*)d_in[3];
    const float* W2 = (const float*)d_in[4];
    const float* b2 = (const float*)d_in[5];
    const float* W3 = (const float*)d_in[6];
    const float* b3 = (const float*)d_in[7];
    const float* g1 = (const float*)d_in[8];
    const float* be1 = (const float*)d_in[9];
    const float* g2 = (const float*)d_in[10];
    const float* be2 = (const float*)d_in[11];
    const float* g3 = (const float*)d_in[12];
    const float* be3 = (const float*)d_in[13];
    float* out = (float*)d_out;

    const int N = N_NODES, E = N_EDGES;
    char* w = (char*)d_ws;
    unsigned short* hb = (unsigned short*)w; w += (size_t)N * 128 * sizeof(unsigned short); // 12.8 MB
    float* mid    = (float*)w;  w += (size_t)N * 128 * sizeof(float);   // 25.6 MB inter-layer f32
    int*   col    = (int*)w;    w += (size_t)E * sizeof(int);           // 2.4 MB
    int*   rowp   = (int*)w;    w += (size_t)(N + 1) * sizeof(int);
    int*   cursor = (int*)w;    w += (size_t)N * sizeof(int);
    int*   deg    = (int*)w;    w += (size_t)N * sizeof(int);
    float* invc   = (float*)w;  w += (size_t)N * sizeof(float);
    int*   parts  = (int*)w;    w += (size_t)SCAN_NBLK * sizeof(int);

    hipMemsetAsync(deg, 0, (size_t)N * sizeof(int), stream);
    count_kernel<<<(E + 255) / 256, 256, 0, stream>>>(ei, deg, E);
    deg_partial_kernel<<<SCAN_NBLK, SCAN_BLOCK, 0, stream>>>(deg, parts, N);
    scan_partials_kernel<<<1, 64, 0, stream>>>(parts, rowp, SCAN_NBLK);
    scan_final_kernel<<<SCAN_NBLK, SCAN_BLOCK, 0, stream>>>(deg, parts, rowp, cursor, invc, N);
    fill_kernel<<<(E + 255) / 256, 256, 0, stream>>>(ei, cursor, col, E);

    const int gemm_blocks = (N + 31) / 32;
    const int agg_blocks  = (N + 3) / 4;   // 4 waves per 256-thread block

    // layer 1
    gemm_kernel<64><<<gemm_blocks, 256, 0, stream>>>(x, W1, b1, hb, N);
    agg_norm_kernel<<<agg_blocks, 256, 0, stream>>>(hb, rowp, col, invc, g1, be1, mid, N);
    // layer 2
    gemm_kernel<128><<<gemm_blocks, 256, 0, stream>>>(mid, W2, b2, hb, N);
    agg_norm_kernel<<<agg_blocks, 256, 0, stream>>>(hb, rowp, col, invc, g2, be2, mid, N);
    // layer 3
    gemm_kernel<128><<<gemm_blocks, 256, 0, stream>>>(mid, W3, b3, hb, N);
    agg_norm_kernel<<<agg_blocks, 256, 0, stream>>>(hb, rowp, col, invc, g3, be3, out, N);
}

// Round 8
// 266.216 us; speedup vs baseline: 1.3333x; 1.3333x over previous
//
#include <hip/hip_runtime.h>
#include <hip/hip_bf16.h>

#define N_NODES 50000
#define N_EDGES 600000
#define HID 128
#define LN_EPS 1e-5f

#define SCAN_BLOCK 1024
#define SCAN_NBLK ((N_NODES + SCAN_BLOCK - 1) / SCAN_BLOCK)   // 49

typedef __attribute__((ext_vector_type(8))) short bf16x8;
typedef __attribute__((ext_vector_type(4))) float f32x4;

// f32 -> bf16 with round-to-nearest-even (values are finite; no NaN guard)
static __device__ __forceinline__ unsigned short f2bf(float f) {
    union { float f; unsigned u; } v; v.f = f;
    unsigned u = v.u;
    u += 0x7fffu + ((u >> 16) & 1u);
    return (unsigned short)(u >> 16);
}

// ---------------------------------------------------------------- CSR build
__global__ __launch_bounds__(256) void count_kernel(const int* __restrict__ ei,
                                                    int* __restrict__ deg, int E) {
    int i = blockIdx.x * blockDim.x + threadIdx.x;
    if (i < E) atomicAdd(&deg[ei[E + i]], 1);
}

__global__ __launch_bounds__(SCAN_BLOCK) void deg_partial_kernel(const int* __restrict__ deg,
                                                                 int* __restrict__ partials, int n) {
    int t = threadIdx.x;
    int i = blockIdx.x * SCAN_BLOCK + t;
    int v = (i < n) ? deg[i] : 0;
    int s = v;
#pragma unroll
    for (int off = 1; off < 64; off <<= 1) s += __shfl_xor(s, off);
    __shared__ int ws[SCAN_BLOCK / 64];
    if ((t & 63) == 0) ws[t >> 6] = s;
    __syncthreads();
    if (t == 0) {
        int tot = 0;
#pragma unroll
        for (int w = 0; w < SCAN_BLOCK / 64; ++w) tot += ws[w];
        partials[blockIdx.x] = tot;
    }
}

__global__ __launch_bounds__(64) void scan_partials_kernel(int* __restrict__ partials,
                                                           int* __restrict__ row_ptr, int nblk) {
    int lane = threadIdx.x;
    int v = (lane < nblk) ? partials[lane] : 0;
    int incl = v;
#pragma unroll
    for (int off = 1; off < 64; off <<= 1) {
        int x = __shfl_up(incl, off);
        if (lane >= off) incl += x;
    }
    if (lane < nblk) partials[lane] = incl - v;     // exclusive block offset
    if (lane == 63) row_ptr[N_NODES] = incl;        // grand total
}

__global__ __launch_bounds__(SCAN_BLOCK) void scan_final_kernel(const int* __restrict__ deg,
                                                                const int* __restrict__ partials,
                                                                int* __restrict__ row_ptr,
                                                                int* __restrict__ cursor,
                                                                float* __restrict__ inv_cnt, int n) {
    int t = threadIdx.x;
    int i = blockIdx.x * SCAN_BLOCK + t;
    int v = (i < n) ? deg[i] : 0;
    int lane = t & 63, wid = t >> 6;
    int incl = v;
#pragma unroll
    for (int off = 1; off < 64; off <<= 1) {
        int x = __shfl_up(incl, off);
        if (lane >= off) incl += x;
    }
    __shared__ int ws[SCAN_BLOCK / 64];
    if (lane == 63) ws[wid] = incl;
    __syncthreads();
    int woff = 0;
    for (int w = 0; w < wid; ++w) woff += ws[w];
    int excl = partials[blockIdx.x] + woff + (incl - v);
    if (i < n) {
        row_ptr[i] = excl;
        cursor[i]  = excl;
        inv_cnt[i] = 1.0f / (float)(v + 1);          // +1 self loop
    }
}

__global__ __launch_bounds__(256) void fill_kernel(const int* __restrict__ ei,
                                                   int* __restrict__ cursor,
                                                   int* __restrict__ col, int E) {
    int i = blockIdx.x * blockDim.x + threadIdx.x;
    if (i < E) {
        int s = ei[i];
        int d = ei[E + i];
        int p = atomicAdd(&cursor[d], 1);
        col[p] = s;
    }
}

// ---------------------------------------------------------------- precision prep
// x [N,64] f32 -> bf16, 8 elems/thread
__global__ __launch_bounds__(256) void cast_x_kernel(const float* __restrict__ x,
                                                     unsigned short* __restrict__ xb, int n8) {
    int i = blockIdx.x * 256 + threadIdx.x;
    if (i < n8) {
        float4 a = ((const float4*)x)[i * 2];
        float4 b = ((const float4*)x)[i * 2 + 1];
        int4 o;
        o.x = (int)f2bf(a.x) | ((int)f2bf(a.y) << 16);
        o.y = (int)f2bf(a.z) | ((int)f2bf(a.w) << 16);
        o.z = (int)f2bf(b.x) | ((int)f2bf(b.y) << 16);
        o.w = (int)f2bf(b.z) | ((int)f2bf(b.w) << 16);
        ((int4*)xb)[i] = o;
    }
}

// W [K,128] f32 -> bf16 swizzled [(k>>3)][col][k&7]
__global__ __launch_bounds__(256) void wswz_kernel(const float* __restrict__ W,
                                                   unsigned short* __restrict__ dst, int K) {
    int i = blockIdx.x * 256 + threadIdx.x;
    if (i < K * 128) {
        int k = i >> 7, col = i & 127;
        dst[(((k >> 3) * 128) + col) * 8 + (k & 7)] = f2bf(W[i]);
    }
}

// ---------------------------------------------------------------- MFMA GEMM
// hb = bf16(A @ W + b). A [N,K] bf16 row-major, Wswz [K/8][128][8] bf16.
// Block: 256 thr = 4 waves, tile 64 rows x 128 cols, full K staged in LDS.
template <int K>
__global__ __launch_bounds__(256) void gemm_mfma_kernel(
    const unsigned short* __restrict__ A,
    const unsigned short* __restrict__ Wswz,
    const float* __restrict__ bias,
    unsigned short* __restrict__ out, int N) {
    __shared__ unsigned short Bl[K * 128];   // swizzled like Wswz
    __shared__ float bl[128];
    int t = threadIdx.x;
    for (int i = t; i < K * 16; i += 256)         // K*128 shorts = K*16 int4
        ((int4*)Bl)[i] = ((const int4*)Wswz)[i];
    if (t < 128) bl[t] = bias[t];
    __syncthreads();

    int lane = t & 63;
    int w = t >> 6;                      // wave 0..3
    int r0 = blockIdx.x * 64 + w * 16;   // wave's 16-row tile
    int colb = lane & 15;
    int kg = lane >> 4;                  // k-octet group 0..3
    int rowa = min(r0 + colb, N - 1);    // A-fragment row (clamped; stores guarded)

    f32x4 acc[8];
#pragma unroll
    for (int c = 0; c < 8; ++c) acc[c] = (f32x4){0.f, 0.f, 0.f, 0.f};

    const bf16x8* Blv = (const bf16x8*)Bl;    // [(k>>3)*128 + col]
    for (int s = 0; s < K; s += 32) {
        bf16x8 afrag = *(const bf16x8*)&A[(size_t)rowa * K + s + kg * 8];
        int kb = (s >> 3) + kg;
#pragma unroll
        for (int c = 0; c < 8; ++c) {
            bf16x8 bfrag = Blv[kb * 128 + c * 16 + colb];
            acc[c] = __builtin_amdgcn_mfma_f32_16x16x32_bf16(afrag, bfrag, acc[c], 0, 0, 0);
        }
    }
    // C/D layout: col = lane&15, row = (lane>>4)*4 + reg
#pragma unroll
    for (int c = 0; c < 8; ++c) {
        int col = c * 16 + colb;
        float bv = bl[col];
#pragma unroll
        for (int r = 0; r < 4; ++r) {
            int ro = r0 + kg * 4 + r;
            if (ro < N) out[(size_t)ro * 128 + col] = f2bf(acc[c][r] + bv);
        }
    }
}

// ------------------------------------------------- aggregate + mean + ReLU + LN
// one wave per node; lane holds cols {2*lane, 2*lane+1}; h rows bf16 (256B).
// BF16OUT: write bf16 (feeds next layer's MFMA GEMM); else f32 (final output).
template <int BF16OUT>
__global__ __launch_bounds__(256) void agg_norm_kernel(
    const unsigned short* __restrict__ hb,  // [N,128] bf16 post-linear
    const int* __restrict__ row_ptr,
    const int* __restrict__ col,
    const float* __restrict__ inv_cnt,
    const float* __restrict__ g, const float* __restrict__ be,
    void* __restrict__ outp, int N) {
    int wave = (int)((blockIdx.x * (size_t)blockDim.x + threadIdx.x) >> 6);
    int lane = threadIdx.x & 63;
    if (wave >= N) return;
    int n = wave;
    const unsigned* h2 = (const unsigned*)hb;   // 2 bf16 per load

    union { unsigned u; float f; } cvt;
    float ax, ay;
    {
        unsigned u = h2[(size_t)n * 64 + lane];            // self loop
        cvt.u = u << 16;          ax = cvt.f;
        cvt.u = u & 0xffff0000u;  ay = cvt.f;
    }
    int beg = row_ptr[n], end = row_ptr[n + 1];
    int cnt = end - beg;
    int myc = (lane < cnt) ? col[beg + lane] : 0;    // covers deg <= 64 (typ. ~12)
    for (int e = 0; e < cnt; ++e) {
        int j = (e < 64) ? __shfl(myc, e) : col[beg + e];
        unsigned u = h2[(size_t)j * 64 + lane];
        cvt.u = u << 16;          ax += cvt.f;
        cvt.u = u & 0xffff0000u;  ay += cvt.f;
    }
    float ic = inv_cnt[n];
    float s0 = fmaxf(ax * ic, 0.0f);
    float s1 = fmaxf(ay * ic, 0.0f);
    float sum = s0 + s1;
    float sq  = s0 * s0 + s1 * s1;
#pragma unroll
    for (int off = 1; off < 64; off <<= 1) {
        sum += __shfl_xor(sum, off);
        sq  += __shfl_xor(sq, off);
    }
    float mu  = sum * (1.0f / 128.0f);
    float var = sq * (1.0f / 128.0f) - mu * mu;
    float rs  = rsqrtf(var + LN_EPS);
    float2 gg = ((const float2*)g)[lane];
    float2 bb = ((const float2*)be)[lane];
    float ox = gg.x * (s0 - mu) * rs + bb.x;
    float oy = gg.y * (s1 - mu) * rs + bb.y;
    if (BF16OUT) {
        unsigned p = (unsigned)f2bf(ox) | ((unsigned)f2bf(oy) << 16);
        ((unsigned*)outp)[(size_t)n * 64 + lane] = p;
    } else {
        float2 o; o.x = ox; o.y = oy;
        ((float2*)outp)[(size_t)n * 64 + lane] = o;
    }
}

// ---------------------------------------------------------------- launch
extern "C" void kernel_launch(void* const* d_in, const int* in_sizes, int n_in,
                              void* d_out, int out_size, void* d_ws, size_t ws_size,
                              hipStream_t stream) {
    const float* x  = (const float*)d_in[0];
    const int*   ei = (const int*)d_in[1];
    const float* W1 = (const float*)d_in[2];
    const float* b1 = (const float*)d_in[3];
    const float* W2 = (const float*)d_in[4];
    const float* b2 = (const float*)d_in[5];
    const float* W3 = (const float*)d_in[6];
    const float* b3 = (const float*)d_in[7];
    const float* g1 = (const float*)d_in[8];
    const float* be1 = (const float*)d_in[9];
    const float* g2 = (const float*)d_in[10];
    const float* be2 = (const float*)d_in[11];
    const float* g3 = (const float*)d_in[12];
    const float* be3 = (const float*)d_in[13];
    float* out = (float*)d_out;

    const int N = N_NODES, E = N_EDGES;
    char* w = (char*)d_ws;
    unsigned short* hb   = (unsigned short*)w; w += (size_t)N * 128 * 2;  // 12.8 MB
    unsigned short* midb = (unsigned short*)w; w += (size_t)N * 128 * 2;  // 12.8 MB
    unsigned short* xb   = (unsigned short*)w; w += (size_t)N * 64 * 2;   // 6.4 MB
    unsigned short* w1s  = (unsigned short*)w; w += (size_t)64 * 128 * 2;
    unsigned short* w2s  = (unsigned short*)w; w += (size_t)128 * 128 * 2;
    unsigned short* w3s  = (unsigned short*)w; w += (size_t)128 * 128 * 2;
    int*   col    = (int*)w;    w += (size_t)E * sizeof(int);             // 2.4 MB
    int*   rowp   = (int*)w;    w += (size_t)(N + 1) * sizeof(int);
    int*   cursor = (int*)w;    w += (size_t)N * sizeof(int);
    int*   deg    = (int*)w;    w += (size_t)N * sizeof(int);
    float* invc   = (float*)w;  w += (size_t)N * sizeof(float);
    int*   parts  = (int*)w;    w += (size_t)SCAN_NBLK * sizeof(int);

    // CSR build
    hipMemsetAsync(deg, 0, (size_t)N * sizeof(int), stream);
    count_kernel<<<(E + 255) / 256, 256, 0, stream>>>(ei, deg, E);
    deg_partial_kernel<<<SCAN_NBLK, SCAN_BLOCK, 0, stream>>>(deg, parts, N);
    scan_partials_kernel<<<1, 64, 0, stream>>>(parts, rowp, SCAN_NBLK);
    scan_final_kernel<<<SCAN_NBLK, SCAN_BLOCK, 0, stream>>>(deg, parts, rowp, cursor, invc, N);
    fill_kernel<<<(E + 255) / 256, 256, 0, stream>>>(ei, cursor, col, E);

    // precision prep
    const int n8 = N * 64 / 8;
    cast_x_kernel<<<(n8 + 255) / 256, 256, 0, stream>>>(x, xb, n8);
    wswz_kernel<<<(64 * 128 + 255) / 256, 256, 0, stream>>>(W1, w1s, 64);
    wswz_kernel<<<(128 * 128 + 255) / 256, 256, 0, stream>>>(W2, w2s, 128);
    wswz_kernel<<<(128 * 128 + 255) / 256, 256, 0, stream>>>(W3, w3s, 128);

    const int gemm_blocks = (N + 63) / 64;   // 782
    const int agg_blocks  = (N + 3) / 4;     // 4 waves per 256-thread block

    // layer 1
    gemm_mfma_kernel<64><<<gemm_blocks, 256, 0, stream>>>(xb, w1s, b1, hb, N);
    agg_norm_kernel<1><<<agg_blocks, 256, 0, stream>>>(hb, rowp, col, invc, g1, be1, midb, N);
    // layer 2
    gemm_mfma_kernel<128><<<gemm_blocks, 256, 0, stream>>>(midb, w2s, b2, hb, N);
    agg_norm_kernel<1><<<agg_blocks, 256, 0, stream>>>(hb, rowp, col, invc, g2, be2, midb, N);
    // layer 3
    gemm_mfma_kernel<128><<<gemm_blocks, 256, 0, stream>>>(midb, w3s, b3, hb, N);
    agg_norm_kernel<0><<<agg_blocks, 256, 0, stream>>>(hb, rowp, col, invc, g3, be3, out, N);
}

// Round 9
// 209.375 us; speedup vs baseline: 1.6952x; 1.2715x over previous
//
#include <hip/hip_runtime.h>
#include <hip/hip_bf16.h>

#define N_NODES 50000
#define N_EDGES 600000
#define HID 128
#define LN_EPS 1e-5f

#define SCAN_BLOCK 1024
#define SCAN_NBLK ((N_NODES + SCAN_BLOCK - 1) / SCAN_BLOCK)   // 49

typedef __attribute__((ext_vector_type(8))) short bf16x8;
typedef __attribute__((ext_vector_type(4))) float f32x4;

// f32 -> bf16 with round-to-nearest-even (values are finite; no NaN guard)
static __device__ __forceinline__ unsigned short f2bf(float f) {
    union { float f; unsigned u; } v; v.f = f;
    unsigned u = v.u;
    u += 0x7fffu + ((u >> 16) & 1u);
    return (unsigned short)(u >> 16);
}

// ---------------------------------------------------------------- CSR build
__global__ __launch_bounds__(256) void count_kernel(const int* __restrict__ ei,
                                                    int* __restrict__ deg, int E) {
    int i = blockIdx.x * blockDim.x + threadIdx.x;
    if (i < E) atomicAdd(&deg[ei[E + i]], 1);
}

__global__ __launch_bounds__(SCAN_BLOCK) void deg_partial_kernel(const int* __restrict__ deg,
                                                                 int* __restrict__ partials, int n) {
    int t = threadIdx.x;
    int i = blockIdx.x * SCAN_BLOCK + t;
    int v = (i < n) ? deg[i] : 0;
    int s = v;
#pragma unroll
    for (int off = 1; off < 64; off <<= 1) s += __shfl_xor(s, off);
    __shared__ int ws[SCAN_BLOCK / 64];
    if ((t & 63) == 0) ws[t >> 6] = s;
    __syncthreads();
    if (t == 0) {
        int tot = 0;
#pragma unroll
        for (int w = 0; w < SCAN_BLOCK / 64; ++w) tot += ws[w];
        partials[blockIdx.x] = tot;
    }
}

__global__ __launch_bounds__(64) void scan_partials_kernel(int* __restrict__ partials,
                                                           int* __restrict__ row_ptr, int nblk) {
    int lane = threadIdx.x;
    int v = (lane < nblk) ? partials[lane] : 0;
    int incl = v;
#pragma unroll
    for (int off = 1; off < 64; off <<= 1) {
        int x = __shfl_up(incl, off);
        if (lane >= off) incl += x;
    }
    if (lane < nblk) partials[lane] = incl - v;     // exclusive block offset
    if (lane == 63) row_ptr[N_NODES] = incl;        // grand total
}

__global__ __launch_bounds__(SCAN_BLOCK) void scan_final_kernel(const int* __restrict__ deg,
                                                                const int* __restrict__ partials,
                                                                int* __restrict__ row_ptr,
                                                                int* __restrict__ cursor,
                                                                float* __restrict__ inv_cnt, int n) {
    int t = threadIdx.x;
    int i = blockIdx.x * SCAN_BLOCK + t;
    int v = (i < n) ? deg[i] : 0;
    int lane = t & 63, wid = t >> 6;
    int incl = v;
#pragma unroll
    for (int off = 1; off < 64; off <<= 1) {
        int x = __shfl_up(incl, off);
        if (lane >= off) incl += x;
    }
    __shared__ int ws[SCAN_BLOCK / 64];
    if (lane == 63) ws[wid] = incl;
    __syncthreads();
    int woff = 0;
    for (int w = 0; w < wid; ++w) woff += ws[w];
    int excl = partials[blockIdx.x] + woff + (incl - v);
    if (i < n) {
        row_ptr[i] = excl;
        cursor[i]  = excl;
        inv_cnt[i] = 1.0f / (float)(v + 1);          // +1 self loop
    }
}

__global__ __launch_bounds__(256) void fill_kernel(const int* __restrict__ ei,
                                                   int* __restrict__ cursor,
                                                   int* __restrict__ col, int E) {
    int i = blockIdx.x * blockDim.x + threadIdx.x;
    if (i < E) {
        int s = ei[i];
        int d = ei[E + i];
        int p = atomicAdd(&cursor[d], 1);
        col[p] = s;
    }
}

// ---------------------------------------------------------------- precision prep
// x [N,64] f32 -> bf16, 8 elems/thread
__global__ __launch_bounds__(256) void cast_x_kernel(const float* __restrict__ x,
                                                     unsigned short* __restrict__ xb, int n8) {
    int i = blockIdx.x * 256 + threadIdx.x;
    if (i < n8) {
        float4 a = ((const float4*)x)[i * 2];
        float4 b = ((const float4*)x)[i * 2 + 1];
        int4 o;
        o.x = (int)f2bf(a.x) | ((int)f2bf(a.y) << 16);
        o.y = (int)f2bf(a.z) | ((int)f2bf(a.w) << 16);
        o.z = (int)f2bf(b.x) | ((int)f2bf(b.y) << 16);
        o.w = (int)f2bf(b.z) | ((int)f2bf(b.w) << 16);
        ((int4*)xb)[i] = o;
    }
}

// W [K,128] f32 -> bf16 swizzled [(k>>3)][col][k&7]
__global__ __launch_bounds__(256) void wswz_kernel(const float* __restrict__ W,
                                                   unsigned short* __restrict__ dst, int K) {
    int i = blockIdx.x * 256 + threadIdx.x;
    if (i < K * 128) {
        int k = i >> 7, col = i & 127;
        dst[(((k >> 3) * 128) + col) * 8 + (k & 7)] = f2bf(W[i]);
    }
}

// ---------------------------------------------------------------- MFMA GEMM
// hb = bf16(A @ W + b). A [N,K] bf16 row-major, Wswz [K/8][128][8] bf16.
// Block: 256 thr = 4 waves, tile 64 rows x 128 cols, full K staged in LDS.
template <int K>
__global__ __launch_bounds__(256) void gemm_mfma_kernel(
    const unsigned short* __restrict__ A,
    const unsigned short* __restrict__ Wswz,
    const float* __restrict__ bias,
    unsigned short* __restrict__ out, int N) {
    __shared__ unsigned short Bl[K * 128];   // swizzled like Wswz
    __shared__ float bl[128];
    int t = threadIdx.x;
    for (int i = t; i < K * 16; i += 256)         // K*128 shorts = K*16 int4
        ((int4*)Bl)[i] = ((const int4*)Wswz)[i];
    if (t < 128) bl[t] = bias[t];
    __syncthreads();

    int lane = t & 63;
    int w = t >> 6;                      // wave 0..3
    int r0 = blockIdx.x * 64 + w * 16;   // wave's 16-row tile
    int colb = lane & 15;
    int kg = lane >> 4;                  // k-octet group 0..3
    int rowa = min(r0 + colb, N - 1);    // A-fragment row (clamped; stores guarded)

    f32x4 acc[8];
#pragma unroll
    for (int c = 0; c < 8; ++c) acc[c] = (f32x4){0.f, 0.f, 0.f, 0.f};

    const bf16x8* Blv = (const bf16x8*)Bl;    // [(k>>3)*128 + col]
    for (int s = 0; s < K; s += 32) {
        bf16x8 afrag = *(const bf16x8*)&A[(size_t)rowa * K + s + kg * 8];
        int kb = (s >> 3) + kg;
#pragma unroll
        for (int c = 0; c < 8; ++c) {
            bf16x8 bfrag = Blv[kb * 128 + c * 16 + colb];
            acc[c] = __builtin_amdgcn_mfma_f32_16x16x32_bf16(afrag, bfrag, acc[c], 0, 0, 0);
        }
    }
    // C/D layout: col = lane&15, row = (lane>>4)*4 + reg
#pragma unroll
    for (int c = 0; c < 8; ++c) {
        int col = c * 16 + colb;
        float bv = bl[col];
#pragma unroll
        for (int r = 0; r < 4; ++r) {
            int ro = r0 + kg * 4 + r;
            if (ro < N) out[(size_t)ro * 128 + col] = f2bf(acc[c][r] + bv);
        }
    }
}

// ------------------------------------------------- aggregate + mean + ReLU + LN
// one wave per node; lane holds cols {2*lane, 2*lane+1}; h rows bf16 (256B).
// Gathers batched 4-wide (independent loads in flight) with predicated masks
// to break the serial load->waitcnt->add chain (latency-bound, round-8 PMC).
// BF16OUT: write bf16 (feeds next layer's MFMA GEMM); else f32 (final output).
template <int BF16OUT>
__global__ __launch_bounds__(256) void agg_norm_kernel(
    const unsigned short* __restrict__ hb,  // [N,128] bf16 post-linear
    const int* __restrict__ row_ptr,
    const int* __restrict__ col,
    const float* __restrict__ inv_cnt,
    const float* __restrict__ g, const float* __restrict__ be,
    void* __restrict__ outp, int N) {
    int wave = (int)((blockIdx.x * (size_t)blockDim.x + threadIdx.x) >> 6);
    int lane = threadIdx.x & 63;
    if (wave >= N) return;
    int n = wave;
    const unsigned* h2 = (const unsigned*)hb;   // 2 bf16 per load

    union { unsigned u; float f; } cvt;
    float ax, ay;
    {
        unsigned u = h2[(size_t)n * 64 + lane];            // self loop
        cvt.u = u << 16;          ax = cvt.f;
        cvt.u = u & 0xffff0000u;  ay = cvt.f;
    }
    int beg = row_ptr[n], end = row_ptr[n + 1];
    int cnt = end - beg;
    int lim = min(cnt, 64);
    int myc = (lane < cnt) ? col[beg + lane] : 0;    // broadcast region (deg <= 64 typ.)

    int nGrp = (lim + 3) >> 2;
    for (int gi = 0; gi < nGrp; ++gi) {
        int e0 = gi * 4;
        int i0 = min(e0 + 0, lim - 1), i1 = min(e0 + 1, lim - 1);
        int i2 = min(e0 + 2, lim - 1), i3 = min(e0 + 3, lim - 1);
        int j0 = __shfl(myc, i0), j1 = __shfl(myc, i1);
        int j2 = __shfl(myc, i2), j3 = __shfl(myc, i3);
        float m1 = (e0 + 1 < lim) ? 1.0f : 0.0f;
        float m2 = (e0 + 2 < lim) ? 1.0f : 0.0f;
        float m3 = (e0 + 3 < lim) ? 1.0f : 0.0f;
        unsigned u0 = h2[(size_t)j0 * 64 + lane];
        unsigned u1 = h2[(size_t)j1 * 64 + lane];
        unsigned u2 = h2[(size_t)j2 * 64 + lane];
        unsigned u3 = h2[(size_t)j3 * 64 + lane];
        cvt.u = u0 << 16;          ax += cvt.f;
        cvt.u = u0 & 0xffff0000u;  ay += cvt.f;
        cvt.u = u1 << 16;          ax = fmaf(m1, cvt.f, ax);
        cvt.u = u1 & 0xffff0000u;  ay = fmaf(m1, cvt.f, ay);
        cvt.u = u2 << 16;          ax = fmaf(m2, cvt.f, ax);
        cvt.u = u2 & 0xffff0000u;  ay = fmaf(m2, cvt.f, ay);
        cvt.u = u3 << 16;          ax = fmaf(m3, cvt.f, ax);
        cvt.u = u3 & 0xffff0000u;  ay = fmaf(m3, cvt.f, ay);
    }
    for (int e = 64; e < cnt; ++e) {                 // rare deg > 64 tail
        int j = col[beg + e];
        unsigned u = h2[(size_t)j * 64 + lane];
        cvt.u = u << 16;          ax += cvt.f;
        cvt.u = u & 0xffff0000u;  ay += cvt.f;
    }
    float ic = inv_cnt[n];
    float s0 = fmaxf(ax * ic, 0.0f);
    float s1 = fmaxf(ay * ic, 0.0f);
    float sum = s0 + s1;
    float sq  = s0 * s0 + s1 * s1;
#pragma unroll
    for (int off = 1; off < 64; off <<= 1) {
        sum += __shfl_xor(sum, off);
        sq  += __shfl_xor(sq, off);
    }
    float mu  = sum * (1.0f / 128.0f);
    float var = sq * (1.0f / 128.0f) - mu * mu;
    float rs  = rsqrtf(var + LN_EPS);
    float2 gg = ((const float2*)g)[lane];
    float2 bb = ((const float2*)be)[lane];
    float ox = gg.x * (s0 - mu) * rs + bb.x;
    float oy = gg.y * (s1 - mu) * rs + bb.y;
    if (BF16OUT) {
        unsigned p = (unsigned)f2bf(ox) | ((unsigned)f2bf(oy) << 16);
        ((unsigned*)outp)[(size_t)n * 64 + lane] = p;
    } else {
        float2 o; o.x = ox; o.y = oy;
        ((float2*)outp)[(size_t)n * 64 + lane] = o;
    }
}

// ---------------------------------------------------------------- launch
extern "C" void kernel_launch(void* const* d_in, const int* in_sizes, int n_in,
                              void* d_out, int out_size, void* d_ws, size_t ws_size,
                              hipStream_t stream) {
    const float* x  = (const float*)d_in[0];
    const int*   ei = (const int*)d_in[1];
    const float* W1 = (const float*)d_in[2];
    const float* b1 = (const float*)d_in[3];
    const float* W2 = (const float*)d_in[4];
    const float* b2 = (const float*)d_in[5];
    const float* W3 = (const float*)d_in[6];
    const float* b3 = (const float*)d_in[7];
    const float* g1 = (const float*)d_in[8];
    const float* be1 = (const float*)d_in[9];
    const float* g2 = (const float*)d_in[10];
    const float* be2 = (const float*)d_in[11];
    const float* g3 = (const float*)d_in[12];
    const float* be3 = (const float*)d_in[13];
    float* out = (float*)d_out;

    const int N = N_NODES, E = N_EDGES;
    char* w = (char*)d_ws;
    unsigned short* hb   = (unsigned short*)w; w += (size_t)N * 128 * 2;  // 12.8 MB
    unsigned short* midb = (unsigned short*)w; w += (size_t)N * 128 * 2;  // 12.8 MB
    unsigned short* xb   = (unsigned short*)w; w += (size_t)N * 64 * 2;   // 6.4 MB
    unsigned short* w1s  = (unsigned short*)w; w += (size_t)64 * 128 * 2;
    unsigned short* w2s  = (unsigned short*)w; w += (size_t)128 * 128 * 2;
    unsigned short* w3s  = (unsigned short*)w; w += (size_t)128 * 128 * 2;
    int*   col    = (int*)w;    w += (size_t)E * sizeof(int);             // 2.4 MB
    int*   rowp   = (int*)w;    w += (size_t)(N + 1) * sizeof(int);
    int*   cursor = (int*)w;    w += (size_t)N * sizeof(int);
    int*   deg    = (int*)w;    w += (size_t)N * sizeof(int);
    float* invc   = (float*)w;  w += (size_t)N * sizeof(float);
    int*   parts  = (int*)w;    w += (size_t)SCAN_NBLK * sizeof(int);

    // CSR build
    hipMemsetAsync(deg, 0, (size_t)N * sizeof(int), stream);
    count_kernel<<<(E + 255) / 256, 256, 0, stream>>>(ei, deg, E);
    deg_partial_kernel<<<SCAN_NBLK, SCAN_BLOCK, 0, stream>>>(deg, parts, N);
    scan_partials_kernel<<<1, 64, 0, stream>>>(parts, rowp, SCAN_NBLK);
    scan_final_kernel<<<SCAN_NBLK, SCAN_BLOCK, 0, stream>>>(deg, parts, rowp, cursor, invc, N);
    fill_kernel<<<(E + 255) / 256, 256, 0, stream>>>(ei, cursor, col, E);

    // precision prep
    const int n8 = N * 64 / 8;
    cast_x_kernel<<<(n8 + 255) / 256, 256, 0, stream>>>(x, xb, n8);
    wswz_kernel<<<(64 * 128 + 255) / 256, 256, 0, stream>>>(W1, w1s, 64);
    wswz_kernel<<<(128 * 128 + 255) / 256, 256, 0, stream>>>(W2, w2s, 128);
    wswz_kernel<<<(128 * 128 + 255) / 256, 256, 0, stream>>>(W3, w3s, 128);

    const int gemm_blocks = (N + 63) / 64;   // 782
    const int agg_blocks  = (N + 3) / 4;     // 4 waves per 256-thread block

    // layer 1
    gemm_mfma_kernel<64><<<gemm_blocks, 256, 0, stream>>>(xb, w1s, b1, hb, N);
    agg_norm_kernel<1><<<agg_blocks, 256, 0, stream>>>(hb, rowp, col, invc, g1, be1, midb, N);
    // layer 2
    gemm_mfma_kernel<128><<<gemm_blocks, 256, 0, stream>>>(midb, w2s, b2, hb, N);
    agg_norm_kernel<1><<<agg_blocks, 256, 0, stream>>>(hb, rowp, col, invc, g2, be2, midb, N);
    // layer 3
    gemm_mfma_kernel<128><<<gemm_blocks, 256, 0, stream>>>(midb, w3s, b3, hb, N);
    agg_norm_kernel<0><<<agg_blocks, 256, 0, stream>>>(hb, rowp, col, invc, g3, be3, out, N);
}

// Round 10
// 195.537 us; speedup vs baseline: 1.8152x; 1.0708x over previous
//
#include <hip/hip_runtime.h>
#include <hip/hip_bf16.h>

#define N_NODES 50000
#define N_EDGES 600000
#define HID 128
#define LN_EPS 1e-5f

#define SCAN_BLOCK 1024
#define SCAN_NBLK ((N_NODES + SCAN_BLOCK - 1) / SCAN_BLOCK)   // 49

typedef __attribute__((ext_vector_type(8))) short bf16x8;
typedef __attribute__((ext_vector_type(4))) float f32x4;

// f32 -> bf16 round-to-nearest-even
static __device__ __forceinline__ unsigned short f2bf(float f) {
    union { float f; unsigned u; } v; v.f = f;
    unsigned u = v.u;
    u += 0x7fffu + ((u >> 16) & 1u);
    return (unsigned short)(u >> 16);
}
static __device__ __forceinline__ float bflo(unsigned u) {
    union { unsigned u; float f; } c; c.u = u << 16; return c.f;
}
static __device__ __forceinline__ float bfhi(unsigned u) {
    union { unsigned u; float f; } c; c.u = u & 0xffff0000u; return c.f;
}

// ---------------------------------------------------------------- CSR build
__global__ __launch_bounds__(256) void count_kernel(const int* __restrict__ ei,
                                                    int* __restrict__ deg, int E) {
    int i = blockIdx.x * blockDim.x + threadIdx.x;
    if (i < E) atomicAdd(&deg[ei[E + i]], 1);
}

__global__ __launch_bounds__(SCAN_BLOCK) void deg_partial_kernel(const int* __restrict__ deg,
                                                                 int* __restrict__ partials, int n) {
    int t = threadIdx.x;
    int i = blockIdx.x * SCAN_BLOCK + t;
    int v = (i < n) ? deg[i] : 0;
    int s = v;
#pragma unroll
    for (int off = 1; off < 64; off <<= 1) s += __shfl_xor(s, off);
    __shared__ int ws[SCAN_BLOCK / 64];
    if ((t & 63) == 0) ws[t >> 6] = s;
    __syncthreads();
    if (t == 0) {
        int tot = 0;
#pragma unroll
        for (int w = 0; w < SCAN_BLOCK / 64; ++w) tot += ws[w];
        partials[blockIdx.x] = tot;
    }
}

__global__ __launch_bounds__(64) void scan_partials_kernel(int* __restrict__ partials,
                                                           int* __restrict__ row_ptr, int nblk) {
    int lane = threadIdx.x;
    int v = (lane < nblk) ? partials[lane] : 0;
    int incl = v;
#pragma unroll
    for (int off = 1; off < 64; off <<= 1) {
        int x = __shfl_up(incl, off);
        if (lane >= off) incl += x;
    }
    if (lane < nblk) partials[lane] = incl - v;
    if (lane == 63) row_ptr[N_NODES] = incl;
}

__global__ __launch_bounds__(SCAN_BLOCK) void scan_final_kernel(const int* __restrict__ deg,
                                                                const int* __restrict__ partials,
                                                                int* __restrict__ row_ptr,
                                                                int* __restrict__ cursor,
                                                                float* __restrict__ inv_cnt, int n) {
    int t = threadIdx.x;
    int i = blockIdx.x * SCAN_BLOCK + t;
    int v = (i < n) ? deg[i] : 0;
    int lane = t & 63, wid = t >> 6;
    int incl = v;
#pragma unroll
    for (int off = 1; off < 64; off <<= 1) {
        int x = __shfl_up(incl, off);
        if (lane >= off) incl += x;
    }
    __shared__ int ws[SCAN_BLOCK / 64];
    if (lane == 63) ws[wid] = incl;
    __syncthreads();
    int woff = 0;
    for (int w = 0; w < wid; ++w) woff += ws[w];
    int excl = partials[blockIdx.x] + woff + (incl - v);
    if (i < n) {
        row_ptr[i] = excl;
        cursor[i]  = excl;
        inv_cnt[i] = 1.0f / (float)(v + 1);
    }
}

__global__ __launch_bounds__(256) void fill_kernel(const int* __restrict__ ei,
                                                   int* __restrict__ cursor,
                                                   int* __restrict__ col, int E) {
    int i = blockIdx.x * blockDim.x + threadIdx.x;
    if (i < E) {
        int s = ei[i];
        int d = ei[E + i];
        int p = atomicAdd(&cursor[d], 1);
        col[p] = s;
    }
}

// ---------------------------------------------------------------- precision prep
__global__ __launch_bounds__(256) void cast_x_kernel(const float* __restrict__ x,
                                                     unsigned short* __restrict__ xb, int n8) {
    int i = blockIdx.x * 256 + threadIdx.x;
    if (i < n8) {
        float4 a = ((const float4*)x)[i * 2];
        float4 b = ((const float4*)x)[i * 2 + 1];
        int4 o;
        o.x = (int)f2bf(a.x) | ((int)f2bf(a.y) << 16);
        o.y = (int)f2bf(a.z) | ((int)f2bf(a.w) << 16);
        o.z = (int)f2bf(b.x) | ((int)f2bf(b.y) << 16);
        o.w = (int)f2bf(b.z) | ((int)f2bf(b.w) << 16);
        ((int4*)xb)[i] = o;
    }
}

__global__ __launch_bounds__(256) void wswz_kernel(const float* __restrict__ W,
                                                   unsigned short* __restrict__ dst, int K) {
    int i = blockIdx.x * 256 + threadIdx.x;
    if (i < K * 128) {
        int k = i >> 7, col = i & 127;
        dst[(((k >> 3) * 128) + col) * 8 + (k & 7)] = f2bf(W[i]);
    }
}

// ---------------------------------------------------------------- MFMA GEMM
template <int K>
__global__ __launch_bounds__(256) void gemm_mfma_kernel(
    const unsigned short* __restrict__ A,
    const unsigned short* __restrict__ Wswz,
    const float* __restrict__ bias,
    unsigned short* __restrict__ out, int N) {
    __shared__ unsigned short Bl[K * 128];
    __shared__ float bl[128];
    int t = threadIdx.x;
    for (int i = t; i < K * 16; i += 256)
        ((int4*)Bl)[i] = ((const int4*)Wswz)[i];
    if (t < 128) bl[t] = bias[t];
    __syncthreads();

    int lane = t & 63;
    int w = t >> 6;
    int r0 = blockIdx.x * 64 + w * 16;
    int colb = lane & 15;
    int kg = lane >> 4;
    int rowa = min(r0 + colb, N - 1);

    f32x4 acc[8];
#pragma unroll
    for (int c = 0; c < 8; ++c) acc[c] = (f32x4){0.f, 0.f, 0.f, 0.f};

    const bf16x8* Blv = (const bf16x8*)Bl;
    for (int s = 0; s < K; s += 32) {
        bf16x8 afrag = *(const bf16x8*)&A[(size_t)rowa * K + s + kg * 8];
        int kb = (s >> 3) + kg;
#pragma unroll
        for (int c = 0; c < 8; ++c) {
            bf16x8 bfrag = Blv[kb * 128 + c * 16 + colb];
            acc[c] = __builtin_amdgcn_mfma_f32_16x16x32_bf16(afrag, bfrag, acc[c], 0, 0, 0);
        }
    }
#pragma unroll
    for (int c = 0; c < 8; ++c) {
        int col = c * 16 + colb;
        float bv = bl[col];
#pragma unroll
        for (int r = 0; r < 4; ++r) {
            int ro = r0 + kg * 4 + r;
            if (ro < N) out[(size_t)ro * 128 + col] = f2bf(acc[c][r] + bv);
        }
    }
}

// ------------------------------------------------- aggregate + mean + ReLU + LN
// 4 nodes per wave, 16 lanes per node, dwordx4 (8 bf16) per lane.
// 4-edge batched gathers: 16 independent row-loads in flight per wave.
template <int BF16OUT>
__global__ __launch_bounds__(256) void agg_norm_kernel(
    const unsigned short* __restrict__ hb,  // [N,128] bf16
    const int* __restrict__ row_ptr,
    const int* __restrict__ col,
    const float* __restrict__ inv_cnt,
    const float* __restrict__ g, const float* __restrict__ be,
    void* __restrict__ outp, int N) {
    int tid  = blockIdx.x * 256 + threadIdx.x;
    int wave = tid >> 6;
    int lane = threadIdx.x & 63;
    int sub  = lane >> 4;          // node slot in wave (0..3)
    int lc   = lane & 15;          // column-group lane (cols lc*8..lc*8+7)
    int n    = wave * 4 + sub;
    bool act = n < N;
    int nc   = act ? n : N - 1;

    const uint4* h4 = (const uint4*)hb;    // one row = 16 uint4

    float a[8];
    {
        uint4 u = h4[(size_t)nc * 16 + lc];          // self loop
        a[0] = bflo(u.x); a[1] = bfhi(u.x);
        a[2] = bflo(u.y); a[3] = bfhi(u.y);
        a[4] = bflo(u.z); a[5] = bfhi(u.z);
        a[6] = bflo(u.w); a[7] = bfhi(u.w);
    }

    int beg = row_ptr[nc], end = row_ptr[nc + 1];
    int cnt = end - beg;
    int lim = min(cnt, 32);
    int c0 = (lc < cnt)      ? col[beg + lc]      : nc;   // preload 32 indices
    int c1 = (16 + lc < cnt) ? col[beg + 16 + lc] : nc;

    int wlim = lim;                                   // max lim across the 4 nodes
    wlim = max(wlim, __shfl_xor(wlim, 16));
    wlim = max(wlim, __shfl_xor(wlim, 32));
    int nGrp = (wlim + 3) >> 2;

    for (int gi = 0; gi < nGrp; ++gi) {
        int e0 = gi * 4;
        int jj[4]; float mm[4];
#pragma unroll
        for (int q = 0; q < 4; ++q) {
            int iq = max(min(e0 + q, lim - 1), 0);
            mm[q] = (e0 + q < lim) ? 1.0f : 0.0f;
            int sl = sub * 16 + (iq & 15);
            int jA = __shfl(c0, sl);
            int jB = __shfl(c1, sl);
            jj[q] = (iq < 16) ? jA : jB;
        }
        uint4 u0 = h4[(size_t)jj[0] * 16 + lc];
        uint4 u1 = h4[(size_t)jj[1] * 16 + lc];
        uint4 u2 = h4[(size_t)jj[2] * 16 + lc];
        uint4 u3 = h4[(size_t)jj[3] * 16 + lc];
#define ACC(U, M)                                                              \
        a[0] = fmaf(M, bflo(U.x), a[0]); a[1] = fmaf(M, bfhi(U.x), a[1]);      \
        a[2] = fmaf(M, bflo(U.y), a[2]); a[3] = fmaf(M, bfhi(U.y), a[3]);      \
        a[4] = fmaf(M, bflo(U.z), a[4]); a[5] = fmaf(M, bfhi(U.z), a[5]);      \
        a[6] = fmaf(M, bflo(U.w), a[6]); a[7] = fmaf(M, bfhi(U.w), a[7]);
        ACC(u0, mm[0]) ACC(u1, mm[1]) ACC(u2, mm[2]) ACC(u3, mm[3])
#undef ACC
    }
    for (int e = 32; e < cnt; ++e) {                  // rare deg > 32 tail
        int j = col[beg + e];
        uint4 u = h4[(size_t)j * 16 + lc];
        a[0] += bflo(u.x); a[1] += bfhi(u.x);
        a[2] += bflo(u.y); a[3] += bfhi(u.y);
        a[4] += bflo(u.z); a[5] += bfhi(u.z);
        a[6] += bflo(u.w); a[7] += bfhi(u.w);
    }

    float ic = inv_cnt[nc];
    float s[8], sum = 0.f, sq = 0.f;
#pragma unroll
    for (int k = 0; k < 8; ++k) {
        s[k] = fmaxf(a[k] * ic, 0.0f);
        sum += s[k];
        sq  += s[k] * s[k];
    }
#pragma unroll
    for (int off = 1; off < 16; off <<= 1) {          // reduce within 16-lane group
        sum += __shfl_xor(sum, off);
        sq  += __shfl_xor(sq, off);
    }
    float mu  = sum * (1.0f / 128.0f);
    float var = sq * (1.0f / 128.0f) - mu * mu;
    float rs  = rsqrtf(var + LN_EPS);

    const float4* gv  = (const float4*)g;
    const float4* bv  = (const float4*)be;
    float4 gA = gv[lc * 2], gB = gv[lc * 2 + 1];
    float4 bA = bv[lc * 2], bB = bv[lc * 2 + 1];
    float o[8];
    o[0] = gA.x * (s[0] - mu) * rs + bA.x;
    o[1] = gA.y * (s[1] - mu) * rs + bA.y;
    o[2] = gA.z * (s[2] - mu) * rs + bA.z;
    o[3] = gA.w * (s[3] - mu) * rs + bA.w;
    o[4] = gB.x * (s[4] - mu) * rs + bB.x;
    o[5] = gB.y * (s[5] - mu) * rs + bB.y;
    o[6] = gB.z * (s[6] - mu) * rs + bB.z;
    o[7] = gB.w * (s[7] - mu) * rs + bB.w;

    if (!act) return;
    if (BF16OUT) {
        uint4 p;
        p.x = (unsigned)f2bf(o[0]) | ((unsigned)f2bf(o[1]) << 16);
        p.y = (unsigned)f2bf(o[2]) | ((unsigned)f2bf(o[3]) << 16);
        p.z = (unsigned)f2bf(o[4]) | ((unsigned)f2bf(o[5]) << 16);
        p.w = (unsigned)f2bf(o[6]) | ((unsigned)f2bf(o[7]) << 16);
        ((uint4*)outp)[(size_t)n * 16 + lc] = p;
    } else {
        float4 f0; f0.x = o[0]; f0.y = o[1]; f0.z = o[2]; f0.w = o[3];
        float4 f1; f1.x = o[4]; f1.y = o[5]; f1.z = o[6]; f1.w = o[7];
        ((float4*)outp)[(size_t)n * 32 + lc * 2]     = f0;
        ((float4*)outp)[(size_t)n * 32 + lc * 2 + 1] = f1;
    }
}

// ---------------------------------------------------------------- launch
extern "C" void kernel_launch(void* const* d_in, const int* in_sizes, int n_in,
                              void* d_out, int out_size, void* d_ws, size_t ws_size,
                              hipStream_t stream) {
    const float* x  = (const float*)d_in[0];
    const int*   ei = (const int*)d_in[1];
    const float* W1 = (const float*)d_in[2];
    const float* b1 = (const float*)d_in[3];
    const float* W2 = (const float*)d_in[4];
    const float* b2 = (const float*)d_in[5];
    const float* W3 = (const float*)d_in[6];
    const float* b3 = (const float*)d_in[7];
    const float* g1 = (const float*)d_in[8];
    const float* be1 = (const float*)d_in[9];
    const float* g2 = (const float*)d_in[10];
    const float* be2 = (const float*)d_in[11];
    const float* g3 = (const float*)d_in[12];
    const float* be3 = (const float*)d_in[13];
    float* out = (float*)d_out;

    const int N = N_NODES, E = N_EDGES;
    char* w = (char*)d_ws;
    unsigned short* hb   = (unsigned short*)w; w += (size_t)N * 128 * 2;
    unsigned short* midb = (unsigned short*)w; w += (size_t)N * 128 * 2;
    unsigned short* xb   = (unsigned short*)w; w += (size_t)N * 64 * 2;
    unsigned short* w1s  = (unsigned short*)w; w += (size_t)64 * 128 * 2;
    unsigned short* w2s  = (unsigned short*)w; w += (size_t)128 * 128 * 2;
    unsigned short* w3s  = (unsigned short*)w; w += (size_t)128 * 128 * 2;
    int*   col    = (int*)w;    w += (size_t)E * sizeof(int);
    int*   rowp   = (int*)w;    w += (size_t)(N + 1) * sizeof(int);
    int*   cursor = (int*)w;    w += (size_t)N * sizeof(int);
    int*   deg    = (int*)w;    w += (size_t)N * sizeof(int);
    float* invc   = (float*)w;  w += (size_t)N * sizeof(float);
    int*   parts  = (int*)w;    w += (size_t)SCAN_NBLK * sizeof(int);

    // CSR build
    hipMemsetAsync(deg, 0, (size_t)N * sizeof(int), stream);
    count_kernel<<<(E + 255) / 256, 256, 0, stream>>>(ei, deg, E);
    deg_partial_kernel<<<SCAN_NBLK, SCAN_BLOCK, 0, stream>>>(deg, parts, N);
    scan_partials_kernel<<<1, 64, 0, stream>>>(parts, rowp, SCAN_NBLK);
    scan_final_kernel<<<SCAN_NBLK, SCAN_BLOCK, 0, stream>>>(deg, parts, rowp, cursor, invc, N);
    fill_kernel<<<(E + 255) / 256, 256, 0, stream>>>(ei, cursor, col, E);

    // precision prep
    const int n8 = N * 64 / 8;
    cast_x_kernel<<<(n8 + 255) / 256, 256, 0, stream>>>(x, xb, n8);
    wswz_kernel<<<(64 * 128 + 255) / 256, 256, 0, stream>>>(W1, w1s, 64);
    wswz_kernel<<<(128 * 128 + 255) / 256, 256, 0, stream>>>(W2, w2s, 128);
    wswz_kernel<<<(128 * 128 + 255) / 256, 256, 0, stream>>>(W3, w3s, 128);

    const int gemm_blocks = (N + 63) / 64;
    const int agg_blocks  = (N + 15) / 16;   // 16 nodes per 256-thread block

    // layer 1
    gemm_mfma_kernel<64><<<gemm_blocks, 256, 0, stream>>>(xb, w1s, b1, hb, N);
    agg_norm_kernel<1><<<agg_blocks, 256, 0, stream>>>(hb, rowp, col, invc, g1, be1, midb, N);
    // layer 2
    gemm_mfma_kernel<128><<<gemm_blocks, 256, 0, stream>>>(midb, w2s, b2, hb, N);
    agg_norm_kernel<1><<<agg_blocks, 256, 0, stream>>>(hb, rowp, col, invc, g2, be2, midb, N);
    // layer 3
    gemm_mfma_kernel<128><<<gemm_blocks, 256, 0, stream>>>(midb, w3s, b3, hb, N);
    agg_norm_kernel<0><<<agg_blocks, 256, 0, stream>>>(hb, rowp, col, invc, g3, be3, out, N);
}